// Round 5
// baseline (387.641 us; speedup 1.0000x reference)
//
#include <hip/hip_runtime.h>

#define N_NODES 100000
#define N_EDGES 1600000
#define D 64

// ---------------- bf16 helpers (raw ushort, RNE) ----------------
__device__ __forceinline__ float bf2f(unsigned short u) {
    return __uint_as_float(((unsigned int)u) << 16);
}
__device__ __forceinline__ unsigned short f2bf(float f) {
    unsigned int i = __float_as_uint(f);
    i += 0x7FFFu + ((i >> 16) & 1u);   // round-to-nearest-even
    return (unsigned short)(i >> 16);
}

// ---------------- CSR build (unchanged from round 4) ----------------

__global__ void zero_cnt(int* __restrict__ cnt) {
    int i = blockIdx.x * 256 + threadIdx.x;
    if (i < N_NODES) cnt[i] = 0;
}

__global__ void count_rank(const int* __restrict__ col, int* __restrict__ cnt,
                           int* __restrict__ rank) {
    int e = blockIdx.x * 256 + threadIdx.x;
    if (e < N_EDGES) rank[e] = atomicAdd(&cnt[col[e]], 1);
}

__global__ void scan1(const int* __restrict__ cnt, int* __restrict__ base,
                      int* __restrict__ bsum) {
    __shared__ int s[256];
    int tid = threadIdx.x;
    int i = blockIdx.x * 256 + tid;
    int v = (i < N_NODES) ? cnt[i] : 0;
    s[tid] = v;
    __syncthreads();
    for (int o = 1; o < 256; o <<= 1) {
        int t = (tid >= o) ? s[tid - o] : 0;
        __syncthreads();
        s[tid] += t;
        __syncthreads();
    }
    if (i < N_NODES) base[i] = s[tid] - v;
    if (tid == 255) bsum[blockIdx.x] = s[255];
}

__global__ void scan2(int* __restrict__ bsum, int* __restrict__ base, int nblocks) {
    __shared__ int s[512];
    int tid = threadIdx.x;
    int v = (tid < nblocks) ? bsum[tid] : 0;
    s[tid] = v;
    __syncthreads();
    for (int o = 1; o < 512; o <<= 1) {
        int t = (tid >= o) ? s[tid - o] : 0;
        __syncthreads();
        s[tid] += t;
        __syncthreads();
    }
    if (tid < nblocks) bsum[tid] = s[tid] - v;
    if (tid == 0) base[N_NODES] = N_EDGES;
}

__global__ void scan3(int* __restrict__ base, const int* __restrict__ bsum) {
    int i = blockIdx.x * 256 + threadIdx.x;
    if (i < N_NODES) base[i] += bsum[blockIdx.x];
}

// epack[base[col]+rank] = {src, raw_weight}
__global__ void scatter_sw(const int* __restrict__ row, const int* __restrict__ col,
                           const float* __restrict__ w, const int* __restrict__ rank,
                           const int* __restrict__ base, int2* __restrict__ epack) {
    int e = blockIdx.x * 256 + threadIdx.x;
    if (e >= N_EDGES) return;
    int c = col[e];
    int pos = base[c] + rank[e];
    int2 p;
    p.x = row[e];
    p.y = __float_as_int(w[e]);
    epack[pos] = p;
}

// dinv[i] = rsqrt(1 + sum of incoming weights)
__global__ void deg_dinv(const int2* __restrict__ epack, const int* __restrict__ base,
                         float* __restrict__ dinv) {
    int i = blockIdx.x * 256 + threadIdx.x;
    if (i >= N_NODES) return;
    float s = 1.0f;
    int en = base[i + 1];
    for (int k = base[i]; k < en; ++k) s += __int_as_float(epack[k].y);
    dinv[i] = rsqrtf(s);
}

// ---------------- prescaled convert: xsb[i][d] = bf16(dinv[i] * x[i][d]) ----------------
__global__ void prescale_bf16(const float4* __restrict__ in4, const float* __restrict__ dinv,
                              ushort4* __restrict__ out4) {
    int gid = blockIdx.x * 256 + threadIdx.x;
    if (gid >= N_NODES * (D / 4)) return;
    float s = dinv[gid >> 4];
    float4 v = in4[gid];
    ushort4 o;
    o.x = f2bf(s * v.x);
    o.y = f2bf(s * v.y);
    o.z = f2bf(s * v.z);
    o.w = f2bf(s * v.w);
    out4[gid] = o;
}

// ---------------- fused layer ----------------
// T[d]   = xsb[node][d] + sum_e w_e * xsb[src_e][d]      (xsb is dinv-prescaled)
// y[d]   = relu( b[d] + dinv[node] * sum_k T[k]*W[k][d] )
// write:  LAST ? f32 y : bf16(dinv[node]*y)  (prescaled for next layer)
// One wave per node, lane = channel. Only ONE sync (after W staging, before edge loop),
// so the 4 waves' edge loops and GEMMs are fully decoupled.
template <bool LAST>
__global__ __launch_bounds__(256, 4)
void gcn_layer(const unsigned short* __restrict__ xsb, const float* __restrict__ W,
               const float* __restrict__ b, const float* __restrict__ dinv,
               const int2* __restrict__ epack, const int* __restrict__ base,
               unsigned short* __restrict__ hb_out, float* __restrict__ f_out) {
    __shared__ float Ws[D * D];
    int t = threadIdx.x;
#pragma unroll
    for (int i = t; i < D * D; i += 256) Ws[i] = W[i];
    __syncthreads();                       // only sync: W ready before any wave's GEMM

    int d = t & 63;
    int node = blockIdx.x * 4 + (t >> 6);  // N_NODES % 4 == 0
    float acc = bf2f(xsb[node * D + d]);   // self term (prescaled)
    int k  = base[node];
    int en = base[node + 1];
#pragma unroll 8
    for (; k < en; ++k) {
        int2 p = epack[k];                              // 8B broadcast, sequential
        acc = fmaf(__int_as_float(p.y), bf2f(xsb[p.x * D + d]), acc);  // 128B line
    }
    // shfl-GEMM: lane k's acc broadcast to all lanes via readlane
    float dot = 0.0f;
#pragma unroll
    for (int kk = 0; kk < D; ++kk)
        dot = fmaf(__shfl(acc, kk), Ws[kk * D + d], dot);
    float s = dinv[node];
    float y = fmaxf(fmaf(s, dot, b[d]), 0.0f);
    if (LAST) f_out[node * D + d] = y;
    else      hb_out[node * D + d] = f2bf(s * y);       // prescale for next layer
}

extern "C" void kernel_launch(void* const* d_in, const int* in_sizes, int n_in,
                              void* d_out, int out_size, void* d_ws, size_t ws_size,
                              hipStream_t stream) {
    const float* x       = (const float*)d_in[0];
    const int*   adj     = (const int*)d_in[1];    // [2][E]
    const float* adj_wts = (const float*)d_in[2];
    const float* W1      = (const float*)d_in[3];
    const float* b1      = (const float*)d_in[4];
    const float* W2      = (const float*)d_in[5];
    const float* b2      = (const float*)d_in[6];
    float* out = (float*)d_out;

    const int* row = adj;
    const int* col = adj + N_EDGES;

    // workspace layout (N_NODES*4 = 400000 B keeps 16B alignment throughout)
    int*   cnt   = (int*)d_ws;                      // N
    int*   rank  = cnt + N_NODES;                   // E
    int*   base  = rank + N_EDGES;                  // N+1 (+pad)
    int*   bsum  = base + N_NODES + 4;              // 512
    float* dinv  = (float*)(bsum + 512);            // N
    int2*  epack = (int2*)(dinv + N_NODES);         // E int2 (12.8 MB)
    unsigned short* xsb = (unsigned short*)(epack + N_EDGES);  // N*D bf16 (12.8 MB)
    unsigned short* hb  = xsb + (size_t)N_NODES * D;           // N*D bf16 (12.8 MB)

    const int nblk_n  = (N_NODES + 255) / 256;      // 391
    const int nblk_e  = (N_EDGES + 255) / 256;      // 6250
    const int nblk_g  = N_NODES / 4;                // 25000
    const int nblk_c  = (N_NODES * 16 + 255) / 256;

    // ---- CSR build (one atomic per edge) ----
    zero_cnt<<<nblk_n, 256, 0, stream>>>(cnt);
    count_rank<<<nblk_e, 256, 0, stream>>>(col, cnt, rank);
    scan1<<<nblk_n, 256, 0, stream>>>(cnt, base, bsum);
    scan2<<<1, 512, 0, stream>>>(bsum, base, nblk_n);
    scan3<<<nblk_n, 256, 0, stream>>>(base, bsum);
    scatter_sw<<<nblk_e, 256, 0, stream>>>(row, col, adj_wts, rank, base, epack);
    deg_dinv<<<nblk_n, 256, 0, stream>>>(epack, base, dinv);

    // ---- x -> dinv-prescaled bf16 ----
    prescale_bf16<<<nblk_c, 256, 0, stream>>>((const float4*)x, dinv, (ushort4*)xsb);

    // ---- fused layers ----
    gcn_layer<false><<<nblk_g, 256, 0, stream>>>(xsb, W1, b1, dinv, epack, base, hb, nullptr);
    gcn_layer<true ><<<nblk_g, 256, 0, stream>>>(hb, W2, b2, dinv, epack, base, nullptr, out);
}

// Round 6
// 311.345 us; speedup vs baseline: 1.2451x; 1.2451x over previous
//
#include <hip/hip_runtime.h>

#define N_NODES 100000
#define N_EDGES 1600000
#define D 64

// ---------------- bf16 helpers (raw ushort, RNE) ----------------
__device__ __forceinline__ float bf2f(unsigned short u) {
    return __uint_as_float(((unsigned int)u) << 16);
}
__device__ __forceinline__ unsigned short f2bf(float f) {
    unsigned int i = __float_as_uint(f);
    i += 0x7FFFu + ((i >> 16) & 1u);   // round-to-nearest-even
    return (unsigned short)(i >> 16);
}
__device__ __forceinline__ float4 bf2f4(ushort4 u) {
    float4 r;
    r.x = bf2f(u.x); r.y = bf2f(u.y); r.z = bf2f(u.z); r.w = bf2f(u.w);
    return r;
}

// ---------------- CSR build (unchanged) ----------------

__global__ void zero_cnt(int* __restrict__ cnt) {
    int i = blockIdx.x * 256 + threadIdx.x;
    if (i < N_NODES) cnt[i] = 0;
}

__global__ void count_rank(const int* __restrict__ col, int* __restrict__ cnt,
                           int* __restrict__ rank) {
    int e = blockIdx.x * 256 + threadIdx.x;
    if (e < N_EDGES) rank[e] = atomicAdd(&cnt[col[e]], 1);
}

__global__ void scan1(const int* __restrict__ cnt, int* __restrict__ base,
                      int* __restrict__ bsum) {
    __shared__ int s[256];
    int tid = threadIdx.x;
    int i = blockIdx.x * 256 + tid;
    int v = (i < N_NODES) ? cnt[i] : 0;
    s[tid] = v;
    __syncthreads();
    for (int o = 1; o < 256; o <<= 1) {
        int t = (tid >= o) ? s[tid - o] : 0;
        __syncthreads();
        s[tid] += t;
        __syncthreads();
    }
    if (i < N_NODES) base[i] = s[tid] - v;
    if (tid == 255) bsum[blockIdx.x] = s[255];
}

__global__ void scan2(int* __restrict__ bsum, int* __restrict__ base, int nblocks) {
    __shared__ int s[512];
    int tid = threadIdx.x;
    int v = (tid < nblocks) ? bsum[tid] : 0;
    s[tid] = v;
    __syncthreads();
    for (int o = 1; o < 512; o <<= 1) {
        int t = (tid >= o) ? s[tid - o] : 0;
        __syncthreads();
        s[tid] += t;
        __syncthreads();
    }
    if (tid < nblocks) bsum[tid] = s[tid] - v;
    if (tid == 0) base[N_NODES] = N_EDGES;
}

__global__ void scan3(int* __restrict__ base, const int* __restrict__ bsum) {
    int i = blockIdx.x * 256 + threadIdx.x;
    if (i < N_NODES) base[i] += bsum[blockIdx.x];
}

__global__ void scatter_sw(const int* __restrict__ row, const int* __restrict__ col,
                           const float* __restrict__ w, const int* __restrict__ rank,
                           const int* __restrict__ base, int2* __restrict__ epack) {
    int e = blockIdx.x * 256 + threadIdx.x;
    if (e >= N_EDGES) return;
    int c = col[e];
    int pos = base[c] + rank[e];
    int2 p;
    p.x = row[e];
    p.y = __float_as_int(w[e]);
    epack[pos] = p;
}

__global__ void deg_dinv(const int2* __restrict__ epack, const int* __restrict__ base,
                         float* __restrict__ dinv) {
    int i = blockIdx.x * 256 + threadIdx.x;
    if (i >= N_NODES) return;
    float s = 1.0f;
    int en = base[i + 1];
    for (int k = base[i]; k < en; ++k) s += __int_as_float(epack[k].y);
    dinv[i] = rsqrtf(s);
}

// ---------------- prescaled convert: xsb[i][d] = bf16(dinv[i] * x[i][d]) ----------------
__global__ void prescale_bf16(const float4* __restrict__ in4, const float* __restrict__ dinv,
                              ushort4* __restrict__ out4) {
    int gid = blockIdx.x * 256 + threadIdx.x;
    if (gid >= N_NODES * (D / 4)) return;
    float s = dinv[gid >> 4];
    float4 v = in4[gid];
    ushort4 o;
    o.x = f2bf(s * v.x);
    o.y = f2bf(s * v.y);
    o.z = f2bf(s * v.z);
    o.w = f2bf(s * v.w);
    out4[gid] = o;
}

// ---------------- fused layer ----------------
// T = xsb[node] + sum_e w_e * xsb[src_e]          (xsb dinv-prescaled, bf16)
// y = relu(b + dinv[node] * (T @ W));  write LAST ? f32 y : bf16(dinv*y)
// One wave per node. Edge loop: 4 edges per iteration — wave splits into
// 4 groups x 16 lanes; lane loads ushort4 (4 channels) of its group's src row,
// so ONE vector load instruction fetches 4 edge rows (512 B).
template <bool LAST>
__global__ __launch_bounds__(256, 4)
void gcn_layer(const unsigned short* __restrict__ xsb, const float* __restrict__ W,
               const float* __restrict__ b, const float* __restrict__ dinv,
               const int2* __restrict__ epack, const int* __restrict__ base,
               unsigned short* __restrict__ hb_out, float* __restrict__ f_out) {
    __shared__ float Ws[D * D];
    __shared__ float xs[4][D];
    int t = threadIdx.x;
#pragma unroll
    for (int i = t; i < D * D; i += 256) Ws[i] = W[i];
    __syncthreads();                        // only block-wide sync (Ws ready)

    int lane = t & 63;
    int ty   = t >> 6;
    int node = blockIdx.x * 4 + ty;         // N_NODES % 4 == 0
    int g    = lane >> 4;                   // edge slot 0..3
    int c4   = (lane & 15) * 4;             // channel quad base

    float4 acc = make_float4(0.f, 0.f, 0.f, 0.f);
    if (g == 0) {                           // self term (prescaled)
        ushort4 sv = *(const ushort4*)(xsb + (size_t)node * D + c4);
        acc = bf2f4(sv);
    }
    int k = base[node], en = base[node + 1];
#pragma unroll 4
    for (; k < en; k += 4) {
        int kg = k + g;
        int kc = (kg < en) ? kg : (en - 1);       // clamp (en>k inside loop)
        int2 p = epack[kc];                       // 4 distinct 8B addrs per wave
        float wv = (kg < en) ? __int_as_float(p.y) : 0.0f;
        ushort4 v = *(const ushort4*)(xsb + (size_t)p.x * D + c4);  // 512B/wave
        float4 xv = bf2f4(v);
        acc.x = fmaf(wv, xv.x, acc.x);
        acc.y = fmaf(wv, xv.y, acc.y);
        acc.z = fmaf(wv, xv.z, acc.z);
        acc.w = fmaf(wv, xv.w, acc.w);
    }
    // fold the 4 edge-slot groups (lanes ^16, ^32)
    acc.x += __shfl_xor(acc.x, 16); acc.y += __shfl_xor(acc.y, 16);
    acc.z += __shfl_xor(acc.z, 16); acc.w += __shfl_xor(acc.w, 16);
    acc.x += __shfl_xor(acc.x, 32); acc.y += __shfl_xor(acc.y, 32);
    acc.z += __shfl_xor(acc.z, 32); acc.w += __shfl_xor(acc.w, 32);
    if (lane < 16) *(float4*)&xs[ty][c4] = acc;   // same-wave write->read: no sync
    int d = lane;
    float dot = 0.0f;
#pragma unroll
    for (int kk = 0; kk < D; ++kk)
        dot = fmaf(xs[ty][kk], Ws[kk * D + d], dot);   // broadcast + stride-1 reads
    float s = dinv[node];
    float y = fmaxf(fmaf(s, dot, b[d]), 0.0f);
    if (LAST) f_out[(size_t)node * D + d] = y;
    else      hb_out[(size_t)node * D + d] = f2bf(s * y);
}

extern "C" void kernel_launch(void* const* d_in, const int* in_sizes, int n_in,
                              void* d_out, int out_size, void* d_ws, size_t ws_size,
                              hipStream_t stream) {
    const float* x       = (const float*)d_in[0];
    const int*   adj     = (const int*)d_in[1];    // [2][E]
    const float* adj_wts = (const float*)d_in[2];
    const float* W1      = (const float*)d_in[3];
    const float* b1      = (const float*)d_in[4];
    const float* W2      = (const float*)d_in[5];
    const float* b2      = (const float*)d_in[6];
    float* out = (float*)d_out;

    const int* row = adj;
    const int* col = adj + N_EDGES;

    // workspace layout (all offsets stay 16B-aligned)
    int*   cnt   = (int*)d_ws;                      // N
    int*   rank  = cnt + N_NODES;                   // E
    int*   base  = rank + N_EDGES;                  // N+1 (+pad)
    int*   bsum  = base + N_NODES + 4;              // 512
    float* dinv  = (float*)(bsum + 512);            // N
    int2*  epack = (int2*)(dinv + N_NODES);         // E int2 (12.8 MB)
    unsigned short* xsb = (unsigned short*)(epack + N_EDGES);  // N*D bf16
    unsigned short* hb  = xsb + (size_t)N_NODES * D;           // N*D bf16

    const int nblk_n  = (N_NODES + 255) / 256;      // 391
    const int nblk_e  = (N_EDGES + 255) / 256;      // 6250
    const int nblk_g  = N_NODES / 4;                // 25000
    const int nblk_c  = (N_NODES * 16 + 255) / 256;

    // ---- CSR build (one atomic per edge) ----
    zero_cnt<<<nblk_n, 256, 0, stream>>>(cnt);
    count_rank<<<nblk_e, 256, 0, stream>>>(col, cnt, rank);
    scan1<<<nblk_n, 256, 0, stream>>>(cnt, base, bsum);
    scan2<<<1, 512, 0, stream>>>(bsum, base, nblk_n);
    scan3<<<nblk_n, 256, 0, stream>>>(base, bsum);
    scatter_sw<<<nblk_e, 256, 0, stream>>>(row, col, adj_wts, rank, base, epack);
    deg_dinv<<<nblk_n, 256, 0, stream>>>(epack, base, dinv);

    // ---- x -> dinv-prescaled bf16 ----
    prescale_bf16<<<nblk_c, 256, 0, stream>>>((const float4*)x, dinv, (ushort4*)xsb);

    // ---- fused layers ----
    gcn_layer<false><<<nblk_g, 256, 0, stream>>>(xsb, W1, b1, dinv, epack, base, hb, nullptr);
    gcn_layer<true ><<<nblk_g, 256, 0, stream>>>(hb, W2, b2, dinv, epack, base, nullptr, out);
}

// Round 7
// 290.904 us; speedup vs baseline: 1.3325x; 1.0703x over previous
//
#include <hip/hip_runtime.h>

#define N_NODES 100000
#define N_EDGES 1600000
#define D 64
#define NBUCK 391          // ceil(N_NODES/256) buckets of 256 dst
#define GBE 391            // edge-pass grid: ceil(N_EDGES/4096)
#define EPB 4096           // edges per block in binA/binC
#define DCAP 6144          // per-bucket capacity (mean 4096, sd 64: +32 sigma)

// ---------------- bf16 helpers ----------------
__device__ __forceinline__ float bf2f(unsigned short u) {
    return __uint_as_float(((unsigned int)u) << 16);
}
__device__ __forceinline__ unsigned short f2bf(float f) {
    unsigned int i = __float_as_uint(f);
    i += 0x7FFFu + ((i >> 16) & 1u);   // RNE
    return (unsigned short)(i >> 16);
}
// fma 8 bf16 channels packed in uint4 into a[0..7]
__device__ __forceinline__ void fma8(float* a, uint4 v, float wv) {
    a[0] = fmaf(wv, __uint_as_float(v.x << 16), a[0]);
    a[1] = fmaf(wv, __uint_as_float(v.x & 0xFFFF0000u), a[1]);
    a[2] = fmaf(wv, __uint_as_float(v.y << 16), a[2]);
    a[3] = fmaf(wv, __uint_as_float(v.y & 0xFFFF0000u), a[3]);
    a[4] = fmaf(wv, __uint_as_float(v.z << 16), a[4]);
    a[5] = fmaf(wv, __uint_as_float(v.z & 0xFFFF0000u), a[5]);
    a[6] = fmaf(wv, __uint_as_float(v.w << 16), a[6]);
    a[7] = fmaf(wv, __uint_as_float(v.w & 0xFFFF0000u), a[7]);
}

// ---------------- radix-binned CSR build (no global atomics) ----------------

// A: per-block bucket histogram (LDS atomics), histT[bucket][block]
__global__ void binA(const int* __restrict__ col, int* __restrict__ histT) {
    __shared__ int h[NBUCK];
    int t = threadIdx.x;
    for (int i = t; i < NBUCK; i += 256) h[i] = 0;
    __syncthreads();
    int e0 = blockIdx.x * EPB;
    for (int i = t; i < EPB; i += 256) {
        int e = e0 + i;
        if (e < N_EDGES) atomicAdd(&h[col[e] >> 8], 1);
    }
    __syncthreads();
    for (int i = t; i < NBUCK; i += 256) histT[i * GBE + blockIdx.x] = h[i];
}

// B1: exclusive scan each bucket-row across blocks; rowtot[bucket]
__global__ void binB1(int* __restrict__ histT, int* __restrict__ rowtot) {
    if (threadIdx.x != 0) return;
    int b = blockIdx.x;
    int acc = 0;
    for (int j = 0; j < GBE; ++j) {
        int v = histT[b * GBE + j];
        histT[b * GBE + j] = acc;
        acc += v;
    }
    rowtot[b] = acc;
}

// B2: exclusive scan of rowtot -> bucketOff
__global__ void binB2(const int* __restrict__ rowtot, int* __restrict__ bucketOff) {
    if (threadIdx.x != 0) return;
    int acc = 0;
    for (int b = 0; b < NBUCK; ++b) { bucketOff[b] = acc; acc += rowtot[b]; }
    bucketOff[NBUCK] = acc;   // == N_EDGES
}

// C: partition edges into bucket-contiguous part_sw{src,w} + part_dlo(dst&255)
__global__ void binC(const int* __restrict__ row, const int* __restrict__ col,
                     const float* __restrict__ w, const int* __restrict__ histT,
                     const int* __restrict__ bucketOff, int2* __restrict__ part_sw,
                     unsigned char* __restrict__ part_dlo) {
    __shared__ int cur[NBUCK];
    int t = threadIdx.x;
    for (int i = t; i < NBUCK; i += 256)
        cur[i] = bucketOff[i] + histT[i * GBE + blockIdx.x];
    __syncthreads();
    int e0 = blockIdx.x * EPB;
    for (int i = t; i < EPB; i += 256) {
        int e = e0 + i;
        if (e >= N_EDGES) continue;
        int c = col[e];
        int pos = atomicAdd(&cur[c >> 8], 1);       // LDS atomic
        int2 p; p.x = row[e]; p.y = __float_as_int(w[e]);
        part_sw[pos] = p;
        part_dlo[pos] = (unsigned char)(c & 255);
    }
}

// D: per-bucket CSR: count/scan/scatter in LDS; emit epack + base
__global__ void binD(const int2* __restrict__ part_sw, const unsigned char* __restrict__ part_dlo,
                     const int* __restrict__ bucketOff, int2* __restrict__ epack,
                     int* __restrict__ base) {
    __shared__ unsigned short dlo[DCAP];
    __shared__ int hist[257];
    __shared__ int cur[256];
    int b = blockIdx.x, t = threadIdx.x;
    int s0 = bucketOff[b], m = bucketOff[b + 1] - s0;
    for (int i = t; i < 257; i += 256) hist[i] = 0;
    __syncthreads();
    for (int i = t; i < m; i += 256) {
        int dl = part_dlo[s0 + i];
        dlo[i] = (unsigned short)dl;
        atomicAdd(&hist[dl], 1);
    }
    __syncthreads();
    if (t == 0) {                                   // exclusive scan of 256
        int acc = 0;
        for (int i = 0; i < 256; ++i) { int v = hist[i]; hist[i] = acc; acc += v; }
        hist[256] = acc;
    }
    __syncthreads();
    cur[t] = hist[t];
    int dst = b * 256 + t;
    if (dst < N_NODES) base[dst] = s0 + hist[t];
    if (b == NBUCK - 1 && t == 0) base[N_NODES] = N_EDGES;
    __syncthreads();
    for (int i = t; i < m; i += 256) {
        int dl = dlo[i];
        int pos = s0 + atomicAdd(&cur[dl], 1);      // LDS atomic
        epack[pos] = part_sw[s0 + i];
    }
}

// dinv[i] = rsqrt(1 + sum of incoming weights)
__global__ void deg_dinv(const int2* __restrict__ epack, const int* __restrict__ base,
                         float* __restrict__ dinv) {
    int i = blockIdx.x * 256 + threadIdx.x;
    if (i >= N_NODES) return;
    float s = 1.0f;
    int en = base[i + 1];
    for (int k = base[i]; k < en; ++k) s += __int_as_float(epack[k].y);
    dinv[i] = rsqrtf(s);
}

// xsb[i][d] = bf16(dinv[i] * x[i][d])
__global__ void prescale_bf16(const float4* __restrict__ in4, const float* __restrict__ dinv,
                              ushort4* __restrict__ out4) {
    int gid = blockIdx.x * 256 + threadIdx.x;
    if (gid >= N_NODES * (D / 4)) return;
    float s = dinv[gid >> 4];
    float4 v = in4[gid];
    ushort4 o;
    o.x = f2bf(s * v.x); o.y = f2bf(s * v.y);
    o.z = f2bf(s * v.z); o.w = f2bf(s * v.w);
    out4[gid] = o;
}

// ---------------- fused layer ----------------
// T = xsb[node] + sum_e w_e*xsb[src_e]; y = relu(b + dinv*(T@W))
// Wave per node: 8 groups x 8 lanes; lane loads uint4 = 8 bf16 channels of its
// group's src row -> one load instr fetches 8 edge rows (1KB/wave).
template <bool LAST>
__global__ __launch_bounds__(256, 4)
void gcn_layer(const unsigned short* __restrict__ xsb, const float* __restrict__ W,
               const float* __restrict__ b, const float* __restrict__ dinv,
               const int2* __restrict__ epack, const int* __restrict__ base,
               unsigned short* __restrict__ hb_out, float* __restrict__ f_out) {
    __shared__ float Ws[D * D];
    __shared__ float xs[4][D];
    int t = threadIdx.x;
#pragma unroll
    for (int i = t; i < D * D; i += 256) Ws[i] = W[i];
    __syncthreads();                        // only block-wide sync

    int lane = t & 63;
    int ty   = t >> 6;
    int node = blockIdx.x * 4 + ty;         // N_NODES % 4 == 0
    int g    = lane >> 3;                   // edge slot 0..7
    int c8   = (lane & 7) * 8;              // channel octet

    float a[8];
#pragma unroll
    for (int j = 0; j < 8; ++j) a[j] = 0.0f;
    if (g == 0) {                           // self term, weight 1 (prescaled)
        uint4 sv = *(const uint4*)(xsb + (size_t)node * D + c8);
        fma8(a, sv, 1.0f);
    }
    int k = base[node], en = base[node + 1];
#pragma unroll 2
    for (; k < en; k += 8) {
        int kg = k + g;
        int kc = (kg < en) ? kg : (en - 1);
        int2 p = epack[kc];                 // 8 distinct 8B addrs per wave
        float wv = (kg < en) ? __int_as_float(p.y) : 0.0f;
        uint4 v = *(const uint4*)(xsb + (size_t)p.x * D + c8);   // 1KB/wave
        fma8(a, v, wv);
    }
#pragma unroll
    for (int j = 0; j < 8; ++j) {           // fold 8 edge-slot groups
        a[j] += __shfl_xor(a[j], 8);
        a[j] += __shfl_xor(a[j], 16);
        a[j] += __shfl_xor(a[j], 32);
    }
    if (lane < 8) {                         // same-wave LDS write->read: no sync
        *(float4*)&xs[ty][lane * 8]     = make_float4(a[0], a[1], a[2], a[3]);
        *(float4*)&xs[ty][lane * 8 + 4] = make_float4(a[4], a[5], a[6], a[7]);
    }
    int d = lane;
    float dot = 0.0f;
#pragma unroll
    for (int kk = 0; kk < D; ++kk)
        dot = fmaf(xs[ty][kk], Ws[kk * D + d], dot);   // broadcast + stride-1
    float s = dinv[node];
    float y = fmaxf(fmaf(s, dot, b[d]), 0.0f);
    if (LAST) f_out[(size_t)node * D + d] = y;
    else      hb_out[(size_t)node * D + d] = f2bf(s * y);
}

extern "C" void kernel_launch(void* const* d_in, const int* in_sizes, int n_in,
                              void* d_out, int out_size, void* d_ws, size_t ws_size,
                              hipStream_t stream) {
    const float* x       = (const float*)d_in[0];
    const int*   adj     = (const int*)d_in[1];    // [2][E]
    const float* adj_wts = (const float*)d_in[2];
    const float* W1      = (const float*)d_in[3];
    const float* b1      = (const float*)d_in[4];
    const float* W2      = (const float*)d_in[5];
    const float* b2      = (const float*)d_in[6];
    float* out = (float*)d_out;

    const int* row = adj;
    const int* col = adj + N_EDGES;

    // workspace layout (every block 16B-aligned)
    char* p = (char*)d_ws;
    int2* epack = (int2*)p;                 p += (size_t)N_EDGES * 8;        // 12.8MB
    unsigned short* xsb = (unsigned short*)p; p += (size_t)N_NODES * D * 2;  // 12.8MB
    unsigned short* hb  = (unsigned short*)p; p += (size_t)N_NODES * D * 2;  // 12.8MB
    int2* part_sw = (int2*)p;               p += (size_t)N_EDGES * 8;        // 12.8MB
    unsigned char* part_dlo = (unsigned char*)p; p += N_EDGES;               // 1.6MB
    int* histT = (int*)p;                   p += (size_t)(NBUCK * GBE + 3) / 4 * 4 * 4; // 0.61MB
    int* rowtot = (int*)p;                  p += 392 * 4;
    int* bucketOff = (int*)p;               p += 392 * 4;
    int* base = (int*)p;                    p += 100004 * 4;
    float* dinv = (float*)p;                p += 100000 * 4;

    const int nblk_n = (N_NODES + 255) / 256;       // 391
    const int nblk_g = N_NODES / 4;                 // 25000
    const int nblk_c = (N_NODES * 16 + 255) / 256;

    // ---- CSR build: LDS-binned radix partition, zero global atomics ----
    binA<<<GBE, 256, 0, stream>>>(col, histT);
    binB1<<<NBUCK, 64, 0, stream>>>(histT, rowtot);
    binB2<<<1, 64, 0, stream>>>(rowtot, bucketOff);
    binC<<<GBE, 256, 0, stream>>>(row, col, adj_wts, histT, bucketOff, part_sw, part_dlo);
    binD<<<NBUCK, 256, 0, stream>>>(part_sw, part_dlo, bucketOff, epack, base);
    deg_dinv<<<nblk_n, 256, 0, stream>>>(epack, base, dinv);

    // ---- x -> dinv-prescaled bf16 ----
    prescale_bf16<<<nblk_c, 256, 0, stream>>>((const float4*)x, dinv, (ushort4*)xsb);

    // ---- fused layers ----
    gcn_layer<false><<<nblk_g, 256, 0, stream>>>(xsb, W1, b1, dinv, epack, base, hb, nullptr);
    gcn_layer<true ><<<nblk_g, 256, 0, stream>>>(hb, W2, b2, dinv, epack, base, nullptr, out);
}

// Round 8
// 234.804 us; speedup vs baseline: 1.6509x; 1.2389x over previous
//
#include <hip/hip_runtime.h>

#define N_NODES 100000
#define N_EDGES 1600000
#define D 64
#define NBUCK 391          // ceil(N_NODES/256) buckets of 256 dst
#define GBE 391            // edge-pass grid: ceil(N_EDGES/4096)
#define EPB 4096           // edges per block in binA/binC
#define DCAP 6144          // per-bucket capacity
#define NTILES 6250        // N_NODES / 16
#define GRID_L 2083        // layer grid (grid-stride over tiles)

typedef __attribute__((ext_vector_type(8))) short bf16x8;
typedef __attribute__((ext_vector_type(4))) float f32x4;

// ---------------- bf16 helpers ----------------
__device__ __forceinline__ unsigned short f2bf(float f) {
    unsigned int i = __float_as_uint(f);
    i += 0x7FFFu + ((i >> 16) & 1u);   // RNE
    return (unsigned short)(i >> 16);
}
// fma 8 bf16 channels packed in uint4 into a[0..7]
__device__ __forceinline__ void fma8(float* a, uint4 v, float wv) {
    a[0] = fmaf(wv, __uint_as_float(v.x << 16), a[0]);
    a[1] = fmaf(wv, __uint_as_float(v.x & 0xFFFF0000u), a[1]);
    a[2] = fmaf(wv, __uint_as_float(v.y << 16), a[2]);
    a[3] = fmaf(wv, __uint_as_float(v.y & 0xFFFF0000u), a[3]);
    a[4] = fmaf(wv, __uint_as_float(v.z << 16), a[4]);
    a[5] = fmaf(wv, __uint_as_float(v.z & 0xFFFF0000u), a[5]);
    a[6] = fmaf(wv, __uint_as_float(v.w << 16), a[6]);
    a[7] = fmaf(wv, __uint_as_float(v.w & 0xFFFF0000u), a[7]);
}

// ---------------- radix-binned CSR build (no global atomics) ----------------

__global__ void binA(const int* __restrict__ col, int* __restrict__ histT) {
    __shared__ int h[NBUCK];
    int t = threadIdx.x;
    for (int i = t; i < NBUCK; i += 256) h[i] = 0;
    __syncthreads();
    int e0 = blockIdx.x * EPB;
    for (int i = t; i < EPB; i += 256) {
        int e = e0 + i;
        if (e < N_EDGES) atomicAdd(&h[col[e] >> 8], 1);
    }
    __syncthreads();
    for (int i = t; i < NBUCK; i += 256) histT[i * GBE + blockIdx.x] = h[i];
}

__global__ void binB1(int* __restrict__ histT, int* __restrict__ rowtot) {
    if (threadIdx.x != 0) return;
    int b = blockIdx.x;
    int acc = 0;
    for (int j = 0; j < GBE; ++j) {
        int v = histT[b * GBE + j];
        histT[b * GBE + j] = acc;
        acc += v;
    }
    rowtot[b] = acc;
}

__global__ void binB2(const int* __restrict__ rowtot, int* __restrict__ bucketOff) {
    if (threadIdx.x != 0) return;
    int acc = 0;
    for (int b = 0; b < NBUCK; ++b) { bucketOff[b] = acc; acc += rowtot[b]; }
    bucketOff[NBUCK] = acc;   // == N_EDGES
}

__global__ void binC(const int* __restrict__ row, const int* __restrict__ col,
                     const float* __restrict__ w, const int* __restrict__ histT,
                     const int* __restrict__ bucketOff, int2* __restrict__ part_sw,
                     unsigned char* __restrict__ part_dlo) {
    __shared__ int cur[NBUCK];
    int t = threadIdx.x;
    for (int i = t; i < NBUCK; i += 256)
        cur[i] = bucketOff[i] + histT[i * GBE + blockIdx.x];
    __syncthreads();
    int e0 = blockIdx.x * EPB;
    for (int i = t; i < EPB; i += 256) {
        int e = e0 + i;
        if (e >= N_EDGES) continue;
        int c = col[e];
        int pos = atomicAdd(&cur[c >> 8], 1);       // LDS atomic
        int2 p; p.x = row[e]; p.y = __float_as_int(w[e]);
        part_sw[pos] = p;
        part_dlo[pos] = (unsigned char)(c & 255);
    }
}

// D: per-bucket CSR in LDS; emits epack + base + dinv (fused weighted degree)
__global__ void binD(const int2* __restrict__ part_sw, const unsigned char* __restrict__ part_dlo,
                     const int* __restrict__ bucketOff, int2* __restrict__ epack,
                     int* __restrict__ base, float* __restrict__ dinv) {
    __shared__ unsigned short dlo[DCAP];
    __shared__ int hist[257];
    __shared__ int cur[256];
    __shared__ float wsum[256];
    int b = blockIdx.x, t = threadIdx.x;
    int s0 = bucketOff[b], m = bucketOff[b + 1] - s0;
    for (int i = t; i < 257; i += 256) hist[i] = 0;
    wsum[t] = 0.0f;
    __syncthreads();
    for (int i = t; i < m; i += 256) {
        int dl = part_dlo[s0 + i];
        dlo[i] = (unsigned short)dl;
        atomicAdd(&hist[dl], 1);
    }
    __syncthreads();
    if (t == 0) {
        int acc = 0;
        for (int i = 0; i < 256; ++i) { int v = hist[i]; hist[i] = acc; acc += v; }
        hist[256] = acc;
    }
    __syncthreads();
    cur[t] = hist[t];
    int dst = b * 256 + t;
    if (dst < N_NODES) base[dst] = s0 + hist[t];
    if (b == NBUCK - 1 && t == 0) base[N_NODES] = N_EDGES;
    __syncthreads();
    for (int i = t; i < m; i += 256) {
        int dl = dlo[i];
        int2 p = part_sw[s0 + i];
        int pos = s0 + atomicAdd(&cur[dl], 1);      // LDS atomic
        epack[pos] = p;
        atomicAdd(&wsum[dl], __int_as_float(p.y));  // LDS float atomic
    }
    __syncthreads();
    if (dst < N_NODES) dinv[dst] = rsqrtf(1.0f + wsum[t]);
}

// xsb[i][d] = bf16(dinv[i] * x[i][d])
__global__ void prescale_bf16(const float4* __restrict__ in4, const float* __restrict__ dinv,
                              ushort4* __restrict__ out4) {
    int gid = blockIdx.x * 256 + threadIdx.x;
    if (gid >= N_NODES * (D / 4)) return;
    float s = dinv[gid >> 4];
    float4 v = in4[gid];
    ushort4 o;
    o.x = f2bf(s * v.x); o.y = f2bf(s * v.y);
    o.z = f2bf(s * v.z); o.w = f2bf(s * v.w);
    out4[gid] = o;
}

// ---------------- fused layer (MFMA epilogue) ----------------
// Per 16-node tile: wave w aggregates nodes 4w..4w+3 (8 edge-slots x 8 lanes,
// uint4 gathers, shfl fold), parks bf16 rows in T[16][72] LDS; after one sync
// each wave computes its 16-col slice of T@W with 2x mfma_f32_16x16x32_bf16.
// Layouts (m89/lab-notes): A row=lane&15, k=8*(lane>>4)+i; B col=lane&15 (via
// transposed Wt), same k; C/D col=lane&15, row=4*(lane>>4)+i.
template <bool LAST>
__global__ __launch_bounds__(256, 4)
void gcn_layer(const unsigned short* __restrict__ xsb, const float* __restrict__ W,
               const float* __restrict__ b, const float* __restrict__ dinv,
               const int2* __restrict__ epack, const int* __restrict__ base,
               unsigned short* __restrict__ hb_out, float* __restrict__ f_out) {
    __shared__ unsigned short Wt[D * 72];       // [d][k] bf16, row-padded (144B)
    __shared__ unsigned short T[2][16 * 72];    // [node_local][k] bf16, dbuf
    int t = threadIdx.x;
    // stage Wt once: W[k][d] f32 -> Wt[d][k] bf16
    for (int idx = t; idx < D * D; idx += 256) {
        int k = idx >> 6, dd = idx & 63;
        Wt[dd * 72 + k] = f2bf(W[idx]);
    }
    __syncthreads();

    int lane  = t & 63;
    int wid   = t >> 6;
    int g     = lane >> 3;               // edge slot 0..7
    int c8    = (lane & 7) * 8;          // channel octet
    int r16   = lane & 15;
    int halfk = (lane >> 4) * 8;         // k offset within K=32 chunk
    // B fragments for this wave's col-tile (cols wid*16 .. +15), once per block
    bf16x8 bf0 = *(const bf16x8*)&Wt[(wid * 16 + r16) * 72 + halfk];
    bf16x8 bf1 = *(const bf16x8*)&Wt[(wid * 16 + r16) * 72 + halfk + 32];
    float bias = b[wid * 16 + r16];

    for (int tile = blockIdx.x; tile < NTILES; tile += GRID_L) {
        int node0 = tile * 16;
        unsigned short* Tb = &T[((unsigned)(tile / GRID_L)) & 1][0];
        // ---- aggregate this wave's 4 nodes ----
        for (int j = 0; j < 4; ++j) {
            int nl = wid * 4 + j;
            int node = node0 + nl;
            float a[8];
#pragma unroll
            for (int q = 0; q < 8; ++q) a[q] = 0.0f;
            if (g == 0) {                        // self term (prescaled, w=1)
                uint4 sv = *(const uint4*)(xsb + (size_t)node * D + c8);
                fma8(a, sv, 1.0f);
            }
            int k = base[node], en = base[node + 1];
            for (; k < en; k += 8) {
                int kg = k + g;
                int kc = (kg < en) ? kg : (en - 1);
                int2 p = epack[kc];
                float wv = (kg < en) ? __int_as_float(p.y) : 0.0f;
                uint4 v = *(const uint4*)(xsb + (size_t)p.x * D + c8);  // 1KB/wave
                fma8(a, v, wv);
            }
#pragma unroll
            for (int q = 0; q < 8; ++q) {        // fold 8 edge-slot groups
                a[q] += __shfl_xor(a[q], 8);
                a[q] += __shfl_xor(a[q], 16);
                a[q] += __shfl_xor(a[q], 32);
            }
            if (lane < 8) {                      // pack row to bf16, park in LDS
                uint4 pk;
                pk.x = ((unsigned)f2bf(a[1]) << 16) | f2bf(a[0]);
                pk.y = ((unsigned)f2bf(a[3]) << 16) | f2bf(a[2]);
                pk.z = ((unsigned)f2bf(a[5]) << 16) | f2bf(a[4]);
                pk.w = ((unsigned)f2bf(a[7]) << 16) | f2bf(a[6]);
                *(uint4*)&Tb[nl * 72 + lane * 8] = pk;
            }
        }
        __syncthreads();                         // T tile complete
        // ---- MFMA: 16 nodes x 16 cols, K=64 in two chunks ----
        bf16x8 af0 = *(const bf16x8*)&Tb[r16 * 72 + halfk];
        bf16x8 af1 = *(const bf16x8*)&Tb[r16 * 72 + halfk + 32];
        f32x4 acc = {0.f, 0.f, 0.f, 0.f};
        acc = __builtin_amdgcn_mfma_f32_16x16x32_bf16(af0, bf0, acc, 0, 0, 0);
        acc = __builtin_amdgcn_mfma_f32_16x16x32_bf16(af1, bf1, acc, 0, 0, 0);
#pragma unroll
        for (int i = 0; i < 4; ++i) {
            int nr = (lane >> 4) * 4 + i;
            int node = node0 + nr;
            float s = dinv[node];
            float y = fmaxf(fmaf(s, acc[i], bias), 0.0f);
            size_t oidx = (size_t)node * D + wid * 16 + r16;
            if (LAST) f_out[oidx] = y;
            else      hb_out[oidx] = f2bf(s * y);   // prescale for next layer
        }
        // no trailing sync needed: T double-buffered, next iter's sync fences
    }
}

extern "C" void kernel_launch(void* const* d_in, const int* in_sizes, int n_in,
                              void* d_out, int out_size, void* d_ws, size_t ws_size,
                              hipStream_t stream) {
    const float* x       = (const float*)d_in[0];
    const int*   adj     = (const int*)d_in[1];    // [2][E]
    const float* adj_wts = (const float*)d_in[2];
    const float* W1      = (const float*)d_in[3];
    const float* b1      = (const float*)d_in[4];
    const float* W2      = (const float*)d_in[5];
    const float* b2      = (const float*)d_in[6];
    float* out = (float*)d_out;

    const int* row = adj;
    const int* col = adj + N_EDGES;

    // workspace layout (every block 16B-aligned)
    char* p = (char*)d_ws;
    int2* epack = (int2*)p;                   p += (size_t)N_EDGES * 8;       // 12.8MB
    unsigned short* xsb = (unsigned short*)p; p += (size_t)N_NODES * D * 2;   // 12.8MB
    unsigned short* hb  = (unsigned short*)p; p += (size_t)N_NODES * D * 2;   // 12.8MB
    int2* part_sw = (int2*)p;                 p += (size_t)N_EDGES * 8;       // 12.8MB
    unsigned char* part_dlo = (unsigned char*)p; p += N_EDGES;                // 1.6MB
    int* histT = (int*)p;                     p += (size_t)(NBUCK * GBE + 3) / 4 * 4 * 4;
    int* rowtot = (int*)p;                    p += 392 * 4;
    int* bucketOff = (int*)p;                 p += 392 * 4;
    int* base = (int*)p;                      p += 100004 * 4;
    float* dinv = (float*)p;                  p += 100000 * 4;

    const int nblk_c = (N_NODES * 16 + 255) / 256;

    // ---- CSR build: LDS-binned radix partition, zero global atomics ----
    binA<<<GBE, 256, 0, stream>>>(col, histT);
    binB1<<<NBUCK, 64, 0, stream>>>(histT, rowtot);
    binB2<<<1, 64, 0, stream>>>(rowtot, bucketOff);
    binC<<<GBE, 256, 0, stream>>>(row, col, adj_wts, histT, bucketOff, part_sw, part_dlo);
    binD<<<NBUCK, 256, 0, stream>>>(part_sw, part_dlo, bucketOff, epack, base, dinv);

    // ---- x -> dinv-prescaled bf16 ----
    prescale_bf16<<<nblk_c, 256, 0, stream>>>((const float4*)x, dinv, (ushort4*)xsb);

    // ---- fused layers (gather agg + MFMA GEMM) ----
    gcn_layer<false><<<GRID_L, 256, 0, stream>>>(xsb, W1, b1, dinv, epack, base, hb, nullptr);
    gcn_layer<true ><<<GRID_L, 256, 0, stream>>>(hb, W2, b2, dinv, epack, base, nullptr, out);
}

// Round 9
// 222.936 us; speedup vs baseline: 1.7388x; 1.0532x over previous
//
#include <hip/hip_runtime.h>

#define N_NODES 100000
#define N_EDGES 1600000
#define D 64
#define NBUCK 391          // ceil(N_NODES/256) buckets of 256 dst
#define GBE 391            // edge-pass grid: ceil(N_EDGES/4096)
#define EPB 4096           // edges per block in binA/binC
#define DCAP 6144          // per-bucket capacity
#define NTILES 6250        // N_NODES / 16

typedef __attribute__((ext_vector_type(8))) short bf16x8;
typedef __attribute__((ext_vector_type(4))) float f32x4;

// ---------------- bf16 helpers ----------------
__device__ __forceinline__ unsigned short f2bf(float f) {
    unsigned int i = __float_as_uint(f);
    i += 0x7FFFu + ((i >> 16) & 1u);   // RNE
    return (unsigned short)(i >> 16);
}
// fma 8 bf16 channels packed in uint4 into a[0..7]
__device__ __forceinline__ void fma8(float* a, uint4 v, float wv) {
    a[0] = fmaf(wv, __uint_as_float(v.x << 16), a[0]);
    a[1] = fmaf(wv, __uint_as_float(v.x & 0xFFFF0000u), a[1]);
    a[2] = fmaf(wv, __uint_as_float(v.y << 16), a[2]);
    a[3] = fmaf(wv, __uint_as_float(v.y & 0xFFFF0000u), a[3]);
    a[4] = fmaf(wv, __uint_as_float(v.z << 16), a[4]);
    a[5] = fmaf(wv, __uint_as_float(v.z & 0xFFFF0000u), a[5]);
    a[6] = fmaf(wv, __uint_as_float(v.w << 16), a[6]);
    a[7] = fmaf(wv, __uint_as_float(v.w & 0xFFFF0000u), a[7]);
}

// ---------------- radix-binned CSR build (no global atomics) ----------------

__global__ void binA(const int* __restrict__ col, int* __restrict__ histT) {
    __shared__ int h[NBUCK];
    int t = threadIdx.x;
    for (int i = t; i < NBUCK; i += 256) h[i] = 0;
    __syncthreads();
    int e0 = blockIdx.x * EPB;
    for (int i = t; i < EPB; i += 256) {
        int e = e0 + i;
        if (e < N_EDGES) atomicAdd(&h[col[e] >> 8], 1);
    }
    __syncthreads();
    for (int i = t; i < NBUCK; i += 256) histT[i * GBE + blockIdx.x] = h[i];
}

__global__ void binB1(int* __restrict__ histT, int* __restrict__ rowtot) {
    if (threadIdx.x != 0) return;
    int b = blockIdx.x;
    int acc = 0;
    for (int j = 0; j < GBE; ++j) {
        int v = histT[b * GBE + j];
        histT[b * GBE + j] = acc;
        acc += v;
    }
    rowtot[b] = acc;
}

__global__ void binB2(const int* __restrict__ rowtot, int* __restrict__ bucketOff) {
    if (threadIdx.x != 0) return;
    int acc = 0;
    for (int b = 0; b < NBUCK; ++b) { bucketOff[b] = acc; acc += rowtot[b]; }
    bucketOff[NBUCK] = acc;   // == N_EDGES
}

__global__ void binC(const int* __restrict__ row, const int* __restrict__ col,
                     const float* __restrict__ w, const int* __restrict__ histT,
                     const int* __restrict__ bucketOff, int2* __restrict__ part_sw,
                     unsigned char* __restrict__ part_dlo) {
    __shared__ int cur[NBUCK];
    int t = threadIdx.x;
    for (int i = t; i < NBUCK; i += 256)
        cur[i] = bucketOff[i] + histT[i * GBE + blockIdx.x];
    __syncthreads();
    int e0 = blockIdx.x * EPB;
    for (int i = t; i < EPB; i += 256) {
        int e = e0 + i;
        if (e >= N_EDGES) continue;
        int c = col[e];
        int pos = atomicAdd(&cur[c >> 8], 1);       // LDS atomic
        int2 p; p.x = row[e]; p.y = __float_as_int(w[e]);
        part_sw[pos] = p;
        part_dlo[pos] = (unsigned char)(c & 255);
    }
}

// D: per-bucket CSR in LDS; emits epack + base + dinv (fused weighted degree)
__global__ void binD(const int2* __restrict__ part_sw, const unsigned char* __restrict__ part_dlo,
                     const int* __restrict__ bucketOff, int2* __restrict__ epack,
                     int* __restrict__ base, float* __restrict__ dinv) {
    __shared__ unsigned short dlo[DCAP];
    __shared__ int hist[257];
    __shared__ int cur[256];
    __shared__ float wsum[256];
    int b = blockIdx.x, t = threadIdx.x;
    int s0 = bucketOff[b], m = bucketOff[b + 1] - s0;
    for (int i = t; i < 257; i += 256) hist[i] = 0;
    wsum[t] = 0.0f;
    __syncthreads();
    for (int i = t; i < m; i += 256) {
        int dl = part_dlo[s0 + i];
        dlo[i] = (unsigned short)dl;
        atomicAdd(&hist[dl], 1);
    }
    __syncthreads();
    if (t == 0) {
        int acc = 0;
        for (int i = 0; i < 256; ++i) { int v = hist[i]; hist[i] = acc; acc += v; }
        hist[256] = acc;
    }
    __syncthreads();
    cur[t] = hist[t];
    int dst = b * 256 + t;
    if (dst < N_NODES) base[dst] = s0 + hist[t];
    if (b == NBUCK - 1 && t == 0) base[N_NODES] = N_EDGES;
    __syncthreads();
    for (int i = t; i < m; i += 256) {
        int dl = dlo[i];
        int2 p = part_sw[s0 + i];
        int pos = s0 + atomicAdd(&cur[dl], 1);      // LDS atomic
        epack[pos] = p;
        atomicAdd(&wsum[dl], __int_as_float(p.y));  // LDS float atomic
    }
    __syncthreads();
    if (dst < N_NODES) dinv[dst] = rsqrtf(1.0f + wsum[t]);
}

// xsb[i][d] = bf16(dinv[i] * x[i][d])
__global__ void prescale_bf16(const float4* __restrict__ in4, const float* __restrict__ dinv,
                              ushort4* __restrict__ out4) {
    int gid = blockIdx.x * 256 + threadIdx.x;
    if (gid >= N_NODES * (D / 4)) return;
    float s = dinv[gid >> 4];
    float4 v = in4[gid];
    ushort4 o;
    o.x = f2bf(s * v.x); o.y = f2bf(s * v.y);
    o.z = f2bf(s * v.z); o.w = f2bf(s * v.w);
    out4[gid] = o;
}

// ---------------- fused layer (2-node interleaved agg + MFMA epilogue) ----------------
// Block = one 16-node tile, 4 waves. Wave w aggregates nodes 4w..4w+3 as TWO
// interleaved pairs (both nodes' epack->gather chains in flight), folds via
// shfl_xor, parks bf16 rows in T[16][72]; after one sync each wave computes its
// 16-col slice of T@W with 2x mfma_f32_16x16x32_bf16. B-fragments come straight
// from global W (L2-hot scalar loads, no LDS staging -> no bank conflicts).
template <bool LAST>
__global__ __launch_bounds__(256, 8)
void gcn_layer(const unsigned short* __restrict__ xsb, const float* __restrict__ W,
               const float* __restrict__ b, const float* __restrict__ dinv,
               const int2* __restrict__ epack, const int* __restrict__ base,
               unsigned short* __restrict__ hb_out, float* __restrict__ f_out) {
    __shared__ unsigned short T[16 * 72];       // [node_local][k] bf16, row-padded
    int t = threadIdx.x;
    int lane  = t & 63;
    int wid   = t >> 6;
    int g     = lane >> 3;               // edge slot 0..7
    int c8    = (lane & 7) * 8;          // channel octet
    int r16   = lane & 15;
    int halfk = (lane >> 4) * 8;         // k offset within K=32 chunk

    // B fragments direct from global W (issued now, consumed at the end)
    int bcol = wid * 16 + r16;
    bf16x8 bf0, bf1;
#pragma unroll
    for (int i = 0; i < 8; ++i) bf0[i] = (short)f2bf(W[(halfk + i) * D + bcol]);
#pragma unroll
    for (int i = 0; i < 8; ++i) bf1[i] = (short)f2bf(W[(halfk + 32 + i) * D + bcol]);
    float bias = b[bcol];

    int node0 = blockIdx.x * 16;
    // ---- aggregate this wave's 4 nodes, as 2 interleaved pairs ----
    for (int jp = 0; jp < 2; ++jp) {
        int nA = node0 + wid * 4 + jp * 2;
        int nB = nA + 1;
        float aA[8], aB[8];
#pragma unroll
        for (int q = 0; q < 8; ++q) { aA[q] = 0.0f; aB[q] = 0.0f; }
        if (g == 0) {                        // self term A (prescaled, w=1)
            uint4 sv = *(const uint4*)(xsb + (size_t)nA * D + c8);
            fma8(aA, sv, 1.0f);
        }
        if (g == 1) {                        // self term B
            uint4 sv = *(const uint4*)(xsb + (size_t)nB * D + c8);
            fma8(aB, sv, 1.0f);
        }
        int kA = base[nA], enA = base[nA + 1];
        int kB = enA,      enB = base[nB + 1];   // CSR rows are contiguous
        while (kA < enA || kB < enB) {
            uint4 vA, vB;
            float wA = 0.0f, wB = 0.0f;
            bool doA = kA < enA, doB = kB < enB;
            if (doA) {
                int kg = kA + g;
                int kc = (kg < enA) ? kg : (enA - 1);
                int2 p = epack[kc];
                wA = (kg < enA) ? __int_as_float(p.y) : 0.0f;
                vA = *(const uint4*)(xsb + (size_t)p.x * D + c8);   // chain 1
            }
            if (doB) {
                int kg = kB + g;
                int kc = (kg < enB) ? kg : (enB - 1);
                int2 p = epack[kc];
                wB = (kg < enB) ? __int_as_float(p.y) : 0.0f;
                vB = *(const uint4*)(xsb + (size_t)p.x * D + c8);   // chain 2
            }
            if (doA) fma8(aA, vA, wA);
            if (doB) fma8(aB, vB, wB);
            kA += 8; kB += 8;
        }
#pragma unroll
        for (int q = 0; q < 8; ++q) {        // fold 8 edge-slot groups (both nodes)
            aA[q] += __shfl_xor(aA[q], 8);
            aB[q] += __shfl_xor(aB[q], 8);
            aA[q] += __shfl_xor(aA[q], 16);
            aB[q] += __shfl_xor(aB[q], 16);
            aA[q] += __shfl_xor(aA[q], 32);
            aB[q] += __shfl_xor(aB[q], 32);
        }
        // pack rows to bf16, park in LDS: lanes 0-7 -> row A, lanes 8-15 -> row B
        if (lane < 16) {
            float* a = (lane < 8) ? aA : aB;
            int nl = wid * 4 + jp * 2 + (lane >> 3);
            int l8 = (lane & 7) * 8;
            uint4 pk;
            pk.x = ((unsigned)f2bf(a[1]) << 16) | f2bf(a[0]);
            pk.y = ((unsigned)f2bf(a[3]) << 16) | f2bf(a[2]);
            pk.z = ((unsigned)f2bf(a[5]) << 16) | f2bf(a[4]);
            pk.w = ((unsigned)f2bf(a[7]) << 16) | f2bf(a[6]);
            *(uint4*)&T[nl * 72 + l8] = pk;
        }
    }
    __syncthreads();                         // T tile complete
    // ---- MFMA: 16 nodes x 16 cols, K=64 in two chunks ----
    bf16x8 af0 = *(const bf16x8*)&T[r16 * 72 + halfk];
    bf16x8 af1 = *(const bf16x8*)&T[r16 * 72 + halfk + 32];
    f32x4 acc = {0.f, 0.f, 0.f, 0.f};
    acc = __builtin_amdgcn_mfma_f32_16x16x32_bf16(af0, bf0, acc, 0, 0, 0);
    acc = __builtin_amdgcn_mfma_f32_16x16x32_bf16(af1, bf1, acc, 0, 0, 0);
#pragma unroll
    for (int i = 0; i < 4; ++i) {
        int nr = (lane >> 4) * 4 + i;
        int node = node0 + nr;
        float s = dinv[node];
        float y = fmaxf(fmaf(s, acc[i], bias), 0.0f);
        size_t oidx = (size_t)node * D + bcol;
        if (LAST) f_out[oidx] = y;
        else      hb_out[oidx] = f2bf(s * y);   // prescale for next layer
    }
}

extern "C" void kernel_launch(void* const* d_in, const int* in_sizes, int n_in,
                              void* d_out, int out_size, void* d_ws, size_t ws_size,
                              hipStream_t stream) {
    const float* x       = (const float*)d_in[0];
    const int*   adj     = (const int*)d_in[1];    // [2][E]
    const float* adj_wts = (const float*)d_in[2];
    const float* W1      = (const float*)d_in[3];
    const float* b1      = (const float*)d_in[4];
    const float* W2      = (const float*)d_in[5];
    const float* b2      = (const float*)d_in[6];
    float* out = (float*)d_out;

    const int* row = adj;
    const int* col = adj + N_EDGES;

    // workspace layout (every block 16B-aligned)
    char* p = (char*)d_ws;
    int2* epack = (int2*)p;                   p += (size_t)N_EDGES * 8;       // 12.8MB
    unsigned short* xsb = (unsigned short*)p; p += (size_t)N_NODES * D * 2;   // 12.8MB
    unsigned short* hb  = (unsigned short*)p; p += (size_t)N_NODES * D * 2;   // 12.8MB
    int2* part_sw = (int2*)p;                 p += (size_t)N_EDGES * 8;       // 12.8MB
    unsigned char* part_dlo = (unsigned char*)p; p += N_EDGES;                // 1.6MB
    int* histT = (int*)p;                     p += (size_t)(NBUCK * GBE + 3) / 4 * 4 * 4;
    int* rowtot = (int*)p;                    p += 392 * 4;
    int* bucketOff = (int*)p;                 p += 392 * 4;
    int* base = (int*)p;                      p += 100004 * 4;
    float* dinv = (float*)p;                  p += 100000 * 4;

    const int nblk_c = (N_NODES * 16 + 255) / 256;

    // ---- CSR build: LDS-binned radix partition, zero global atomics ----
    binA<<<GBE, 256, 0, stream>>>(col, histT);
    binB1<<<NBUCK, 64, 0, stream>>>(histT, rowtot);
    binB2<<<1, 64, 0, stream>>>(rowtot, bucketOff);
    binC<<<GBE, 256, 0, stream>>>(row, col, adj_wts, histT, bucketOff, part_sw, part_dlo);
    binD<<<NBUCK, 256, 0, stream>>>(part_sw, part_dlo, bucketOff, epack, base, dinv);

    // ---- x -> dinv-prescaled bf16 ----
    prescale_bf16<<<nblk_c, 256, 0, stream>>>((const float4*)x, dinv, (ushort4*)xsb);

    // ---- fused layers (interleaved gather agg + MFMA GEMM) ----
    gcn_layer<false><<<NTILES, 256, 0, stream>>>(xsb, W1, b1, dinv, epack, base, hb, nullptr);
    gcn_layer<true ><<<NTILES, 256, 0, stream>>>(hb, W2, b2, dinv, epack, base, nullptr, out);
}